// Round 21
// baseline (70.990 us; speedup 1.0000x reference)
//
#include <hip/hip_runtime.h>

// MFMA fragment layouts (gfx950, 16x16 family, verified m89):
//   A-frag (M16,K32): lane l holds A[row=l&15][k=(l>>4)*8+e], e=0..7
//   B-frag (K32,N16): lane l holds B[k=(l>>4)*8+e][col=l&15]
//   C/D:              col=l&15, row=(l>>4)*4+reg
// h subtiled: hS[jt][et][16][16] f16 (512 B subtiles).
// ds_read_b64_tr_b16 (verified v6/v8): lane addr = subtile + lg*128 + ll*8;
// elem e = subtile[lg*4+e][ll] — the K16 PV A-frag.
//
// v21 = v20 with the 7 tr-reads HOISTED to the top of the tile body
// (before the score MFMAs). Mechanism: tr data is score-independent; issuing
// first lets the DS pipe retire them under the ~200-cy score phase, so the
// LGKM0 drain before PV is ~free instead of paying ~7 tr retirements on the
// critical path per tile (361 tiles/block). HW lgkm counter counts ALL
// outstanding DS ops (FIFO), so the compiler's counted waits before the
// score MFMAs become conservative-but-correct; our LGKM0 before PV is the
// rule-#18 fence. Single tr buffer: no WAR (prior PV consumed tr before
// these TRDs issue in program order). Plus v_max3 for the lmax tree.
// Everything else identical to v20/v18 (flattened balance, defer-max,
// exp2-domain, setprio, 768 thr / 12 waves / grid 256, LDS 153.6 KB).

typedef _Float16 half8 __attribute__((ext_vector_type(8)));
typedef _Float16 half4 __attribute__((ext_vector_type(4)));
typedef float f32x4 __attribute__((ext_vector_type(4)));

constexpr int B_ = 256, N_ = 300, E_ = 100;
constexpr float NEGINF = -9e15f;
constexpr float PADV   = -3e38f;
constexpr float LOG2E  = 1.44269504088896f;

// LDS: hS [19][7][16][16] f16 (68096) | A16 [4][128] f16 @68096 (1024)
//      | 11 partial regions x 64 lanes x 30 f32 = 84480 B @69120
constexpr int PART_OFF  = 69120;
constexpr int LDS_BYTES = 69120 + 11 * 7680;   // 153600 <= 163840

#define TRD(dst, addr, off) \
  asm volatile("ds_read_b64_tr_b16 %0, %1 offset:" #off : "=v"(dst) : "v"(addr))
#define LGKM0 do { asm volatile("s_waitcnt lgkmcnt(0)" ::: "memory"); \
                   __builtin_amdgcn_sched_barrier(0); } while (0)

__global__ __launch_bounds__(768)
void gat_flash19(const float* __restrict__ H, const int* __restrict__ ADJ,
                 const float* __restrict__ A, float* __restrict__ OUT) {
  extern __shared__ char smraw[];
  _Float16* hS   = (_Float16*)smraw;
  _Float16* A16  = (_Float16*)(smraw + 68096);
  float*    part = (float*)(smraw + PART_OFF);

  const int b = blockIdx.x;
  const int tid = threadIdx.x;
  const int w = tid >> 6, lane = tid & 63;
  const int lg = lane >> 4, ll = lane & 15;

  const float* Hb  = H + (size_t)b * (N_ * E_);
  const int*   AJb = ADJ + (size_t)b * (N_ * N_);

  // ---------------- stage h into subtiled LDS (zero-padded) ----------------
  for (int u = tid; u < 304 * 14; u += 768) {
    const int j = u / 14, hr = u % 14;
    half8 v;
#pragma unroll
    for (int e = 0; e < 8; ++e) {
      const int d = hr * 8 + e;
      v[e] = (_Float16)((j < N_ && d < E_) ? Hb[j * E_ + d] : 0.f);
    }
    *(half8*)&hS[(((j >> 4) * 7 + (hr >> 1)) << 8) + ((j & 15) << 4) + ((hr & 1) << 3)] = v;
  }
  if (tid < 64) {
    const int k = tid >> 4, oct = tid & 15;
    half8 v;
#pragma unroll
    for (int e = 0; e < 8; ++e) {
      const int d = oct * 8 + e;
      v[e] = (_Float16)((d < E_) ? A[k * E_ + d] * LOG2E : 0.f);   // log2-domain
    }
    *(half8*)&A16[k * 128 + oct * 8] = v;
  }
  __syncthreads();

  const unsigned ldsbase = (unsigned)(size_t)(void*)hS;
  const unsigned trlane  = (unsigned)(ll * 8 + lg * 128);

  half8 g[3][4];
  half4 gt[4];
  float m, lsum;
  f32x4 acc[7];
  const int* ajrow = AJb;

  auto prep_strip = [&](int s) {
    const int irow = s * 16 + ll;
    const int irc  = irow < N_ ? irow : N_ - 1;
    ajrow = AJb + (size_t)irc * N_;
#pragma unroll
    for (int db = 0; db < 3; ++db) {
      const int doct = db * 4 + lg;
      const half8 hi = *(const half8*)&hS[((s * 7 + (doct >> 1)) << 8) + (ll << 4) + ((doct & 1) << 3)];
#pragma unroll
      for (int k = 0; k < 4; ++k)
        g[db][k] = hi * *(const half8*)&A16[k * 128 + doct * 8];
    }
    const half4 hit = *(const half4*)&hS[((s * 7 + 6) << 8) + (ll << 4) + lg * 4];
#pragma unroll
    for (int k = 0; k < 4; ++k)
      gt[k] = hit * *(const half4*)&A16[k * 128 + 96 + lg * 4];
    m = PADV; lsum = 0.f;
#pragma unroll
    for (int t = 0; t < 7; ++t) acc[t] = (f32x4){0.f, 0.f, 0.f, 0.f};
  };

  auto load_adj = [&](int jt) -> int4 {
    int jc = jt * 16 + lg * 4;
    if (jc > N_ - 4) jc = N_ - 4;
    return *(const int4*)(ajrow + jc);
  };

  auto tile_body = [&](int jt, int4 av, bool tail) {
    // ---- tr reads FIRST: retire under the whole score phase ----
    const unsigned trb = ldsbase + (unsigned)(jt * 3584) + trlane;
    half4 tr[7];
    TRD(tr[0], trb, 0);    TRD(tr[1], trb, 512);  TRD(tr[2], trb, 1024);
    TRD(tr[3], trb, 1536); TRD(tr[4], trb, 2048); TRD(tr[5], trb, 2560);
    TRD(tr[6], trb, 3072);

    f32x4 c0 = {0.f, 0.f, 0.f, 0.f}, c1 = c0, c2 = c0, c3 = c0;
    __builtin_amdgcn_s_setprio(1);
#pragma unroll
    for (int db = 0; db < 3; ++db) {
      const int doct = db * 4 + lg;
      const half8 aj = *(const half8*)&hS[((jt * 7 + (doct >> 1)) << 8) + (ll << 4) + ((doct & 1) << 3)];
      c0 = __builtin_amdgcn_mfma_f32_16x16x32_f16(aj, g[db][0], c0, 0, 0, 0);
      c1 = __builtin_amdgcn_mfma_f32_16x16x32_f16(aj, g[db][1], c1, 0, 0, 0);
      c2 = __builtin_amdgcn_mfma_f32_16x16x32_f16(aj, g[db][2], c2, 0, 0, 0);
      c3 = __builtin_amdgcn_mfma_f32_16x16x32_f16(aj, g[db][3], c3, 0, 0, 0);
    }
    {
      const half4 ajt = *(const half4*)&hS[((jt * 7 + 6) << 8) + (ll << 4) + lg * 4];
      c0 = __builtin_amdgcn_mfma_f32_16x16x16f16(ajt, gt[0], c0, 0, 0, 0);
      c1 = __builtin_amdgcn_mfma_f32_16x16x16f16(ajt, gt[1], c1, 0, 0, 0);
      c2 = __builtin_amdgcn_mfma_f32_16x16x16f16(ajt, gt[2], c2, 0, 0, 0);
      c3 = __builtin_amdgcn_mfma_f32_16x16x16f16(ajt, gt[3], c3, 0, 0, 0);
    }
    __builtin_amdgcn_s_setprio(0);
    const int va[4] = {av.x, av.y, av.z, av.w};
    float sv[4];
#pragma unroll
    for (int r = 0; r < 4; ++r) {
      const float e = (va[r] == 1) ? c0[r] : (va[r] == 2) ? c1[r]
                     : (va[r] == 3) ? c2[r] : c3[r];
      sv[r] = (va[r] == 0) ? NEGINF : fmaxf(e, 0.2f * e);
    }
    if (tail && lg == 3) { sv[0] = PADV; sv[1] = PADV; sv[2] = PADV; sv[3] = PADV; }

    float lmax;
    asm("v_max3_f32 %0, %1, %2, %3" : "=v"(lmax) : "v"(sv[0]), "v"(sv[1]), "v"(sv[2]));
    lmax = fmaxf(lmax, sv[3]);
    if (__any(lmax > m + 8.f)) {
      float tmax = fmaxf(lmax, __shfl_xor(lmax, 16));
      tmax = fmaxf(tmax, __shfl_xor(tmax, 32));
      const float nm = fmaxf(m, tmax);
      const float f = exp2f(m - nm);
      m = nm; lsum *= f;
#pragma unroll
      for (int t = 0; t < 7; ++t) {
        acc[t][0] *= f; acc[t][1] *= f; acc[t][2] *= f; acc[t][3] *= f;
      }
    }
    const float p0 = exp2f(sv[0] - m), p1 = exp2f(sv[1] - m);
    const float p2 = exp2f(sv[2] - m), p3 = exp2f(sv[3] - m);
    lsum += (p0 + p1) + (p2 + p3);
    half4 pb;
    pb[0] = (_Float16)p0; pb[1] = (_Float16)p1;
    pb[2] = (_Float16)p2; pb[3] = (_Float16)p3;

    LGKM0;   // rule #18 — should now be ~free (trs retired long ago)
    __builtin_amdgcn_s_setprio(1);
#pragma unroll
    for (int t = 0; t < 7; ++t)
      acc[t] = __builtin_amdgcn_mfma_f32_16x16x16f16(tr[t], pb, acc[t], 0, 0, 0);
    __builtin_amdgcn_s_setprio(0);
  };

  auto store_rows = [&](int s) {
    float ls = lsum;
    ls += __shfl_xor(ls, 16);
    ls += __shfl_xor(ls, 32);
    const float rv = 1.f / ls;
    const int irow = s * 16 + ll;
    if (irow < N_) {
      float* orow = OUT + ((size_t)b * N_ + irow) * E_;
#pragma unroll
      for (int t = 0; t < 7; ++t) {
        const int e0 = t * 16 + lg * 4;
        if (e0 < E_) {
          f32x4 o = acc[t];
          o[0] *= rv; o[1] *= rv; o[2] *= rv; o[3] *= rv;
          *(f32x4*)&orow[e0] = o;
        }
      }
    }
  };

  // ============ flattened tile-space: wave w owns units [30w, u1) ==========
  int u = 30 * w;
  const int u1 = (w == 11) ? 361 : (u + 30);
  bool held = false;
  int s_held = 0;

  while (u < u1) {
    const int s  = u / 19;
    const int j0 = u - 19 * s;
    const int j1 = (19 < j0 + (u1 - u)) ? 19 : (j0 + (u1 - u));
    prep_strip(s);
    int4 av = load_adj(j0);
    for (int jt = j0; jt < j1; ++jt) {
      const int4 nv = (jt + 1 < j1) ? load_adj(jt + 1) : av;
      tile_body(jt, av, jt == 18);
      av = nv;
    }
    if (j0 > 0) {
      // tail segment of a split strip -> write partial to region[w-1]
      float* dst = part + (size_t)(w - 1) * 1920 + lane * 30;
#pragma unroll
      for (int t = 0; t < 7; ++t) {
        dst[4 * t + 0] = acc[t][0]; dst[4 * t + 1] = acc[t][1];
        dst[4 * t + 2] = acc[t][2]; dst[4 * t + 3] = acc[t][3];
      }
      dst[28] = m; dst[29] = lsum;
    } else if (j1 < 19) {
      held = true; s_held = s;       // head segment: merge after barrier
    } else {
      store_rows(s);                 // whole strip
    }
    u += j1 - j0;
  }

  __syncthreads();

  if (held) {
    // merge region[w] (written by wave w+1's tail segment of s_held)
    const float* src = part + (size_t)w * 1920 + lane * 30;
    const float mq = src[28], lq = src[29];
    const float M  = fmaxf(m, mq);
    const float f0 = exp2f(m - M), f1 = exp2f(mq - M);
    m = M;
    lsum = lsum * f0 + lq * f1;
#pragma unroll
    for (int t = 0; t < 7; ++t) {
      acc[t][0] = acc[t][0] * f0 + src[4 * t + 0] * f1;
      acc[t][1] = acc[t][1] * f0 + src[4 * t + 1] * f1;
      acc[t][2] = acc[t][2] * f0 + src[4 * t + 2] * f1;
      acc[t][3] = acc[t][3] * f0 + src[4 * t + 3] * f1;
    }
    store_rows(s_held);
  }
}

extern "C" void kernel_launch(void* const* d_in, const int* in_sizes, int n_in,
                              void* d_out, int out_size, void* d_ws, size_t ws_size,
                              hipStream_t stream) {
  const float* H  = (const float*)d_in[0];
  const int*   AJ = (const int*)d_in[1];
  const float* A  = (const float*)d_in[2];
  float* OUT = (float*)d_out;

  (void)hipFuncSetAttribute(reinterpret_cast<const void*>(gat_flash19),
                            hipFuncAttributeMaxDynamicSharedMemorySize,
                            LDS_BYTES);
  gat_flash19<<<B_, 768, LDS_BYTES, stream>>>(H, AJ, A, OUT);
}

// Round 22
// 67.488 us; speedup vs baseline: 1.0519x; 1.0519x over previous
//
#include <hip/hip_runtime.h>

// FINAL: v20 (best measured: 67.52 us, absmax 0.0430 vs threshold 0.108).
//
// MFMA fragment layouts (gfx950, 16x16 family, verified m89):
//   A-frag (M16,K32): lane l holds A[row=l&15][k=(l>>4)*8+e], e=0..7
//   B-frag (K32,N16): lane l holds B[k=(l>>4)*8+e][col=l&15]
//   C/D:              col=l&15, row=(l>>4)*4+reg
// h subtiled: hS[jt][et][16][16] f16 (512 B subtiles).
// ds_read_b64_tr_b16 (verified v6/v8): lane addr = subtile + lg*128 + ll*8;
// elem e = subtile[lg*4+e][ll] — the K16 PV A-frag.
//
// Structure: swapped-QK scores (S^T = mfma(h_j, h_i.*A_k)) so the score
// C-frag IS the PV B-frag — softmax fully in registers, no P buffer, no
// main-loop barriers. Per-tile: 16 score MFMA (4 edge-type chains), select
// by adj + leaky-relu in regs, 7 hw-transpose reads for h^T, deferred-max
// online softmax (THR=8, exp2-domain; A16 pre-scaled by log2e at staging),
// one lgkmcnt(0)+sched_barrier fence (rule #18), 14 PV MFMA.
// Balance: flattened tile-space — wave w owns units [30w, 30(w+1)) of the
// 19x19 (strip,tile) space; tail segment writes partial (m,lsum,acc28) to
// region[w-1] (lane*30 f32 layout); head segment merges region[w] after ONE
// barrier via exact online-softmax combine; whole strips store directly.
// Geometry: 768 thr / 12 waves / grid 256 (1 block/batch), NO launch-bounds
// reg cap (84 arch + 48 acc, spill-free; any forced cap or wider live set
// spills — verified v5/v6/v14/v15/v16/v19/v21). LDS 153.6 KB.
// Plateau: v13/v18/v20 all 67.5-68.5 us; no pipe >40% — latency-bound by
// (LDS -> 1 block/CU) x (VGPR -> 3 waves/SIMD) x per-tile serial chain.

typedef _Float16 half8 __attribute__((ext_vector_type(8)));
typedef _Float16 half4 __attribute__((ext_vector_type(4)));
typedef float f32x4 __attribute__((ext_vector_type(4)));

constexpr int B_ = 256, N_ = 300, E_ = 100;
constexpr float NEGINF = -9e15f;
constexpr float PADV   = -3e38f;
constexpr float LOG2E  = 1.44269504088896f;

// LDS: hS [19][7][16][16] f16 (68096) | A16 [4][128] f16 @68096 (1024)
//      | 11 partial regions x 64 lanes x 30 f32 = 84480 B @69120
constexpr int PART_OFF  = 69120;
constexpr int LDS_BYTES = 69120 + 11 * 7680;   // 153600 <= 163840

#define TRD(dst, addr, off) \
  asm volatile("ds_read_b64_tr_b16 %0, %1 offset:" #off : "=v"(dst) : "v"(addr))
#define LGKM0 do { asm volatile("s_waitcnt lgkmcnt(0)" ::: "memory"); \
                   __builtin_amdgcn_sched_barrier(0); } while (0)

__global__ __launch_bounds__(768)
void gat_final(const float* __restrict__ H, const int* __restrict__ ADJ,
               const float* __restrict__ A, float* __restrict__ OUT) {
  extern __shared__ char smraw[];
  _Float16* hS   = (_Float16*)smraw;
  _Float16* A16  = (_Float16*)(smraw + 68096);
  float*    part = (float*)(smraw + PART_OFF);

  const int b = blockIdx.x;
  const int tid = threadIdx.x;
  const int w = tid >> 6, lane = tid & 63;
  const int lg = lane >> 4, ll = lane & 15;

  const float* Hb  = H + (size_t)b * (N_ * E_);
  const int*   AJb = ADJ + (size_t)b * (N_ * N_);

  // ---------------- stage h into subtiled LDS (zero-padded) ----------------
  for (int u = tid; u < 304 * 14; u += 768) {
    const int j = u / 14, hr = u % 14;
    half8 v;
#pragma unroll
    for (int e = 0; e < 8; ++e) {
      const int d = hr * 8 + e;
      v[e] = (_Float16)((j < N_ && d < E_) ? Hb[j * E_ + d] : 0.f);
    }
    *(half8*)&hS[(((j >> 4) * 7 + (hr >> 1)) << 8) + ((j & 15) << 4) + ((hr & 1) << 3)] = v;
  }
  if (tid < 64) {
    const int k = tid >> 4, oct = tid & 15;
    half8 v;
#pragma unroll
    for (int e = 0; e < 8; ++e) {
      const int d = oct * 8 + e;
      v[e] = (_Float16)((d < E_) ? A[k * E_ + d] * LOG2E : 0.f);   // log2-domain
    }
    *(half8*)&A16[k * 128 + oct * 8] = v;
  }
  __syncthreads();

  const unsigned ldsbase = (unsigned)(size_t)(void*)hS;
  const unsigned trlane  = (unsigned)(ll * 8 + lg * 128);

  half8 g[3][4];
  half4 gt[4];
  float m, lsum;
  f32x4 acc[7];
  const int* ajrow = AJb;

  auto prep_strip = [&](int s) {
    const int irow = s * 16 + ll;
    const int irc  = irow < N_ ? irow : N_ - 1;
    ajrow = AJb + (size_t)irc * N_;
#pragma unroll
    for (int db = 0; db < 3; ++db) {
      const int doct = db * 4 + lg;
      const half8 hi = *(const half8*)&hS[((s * 7 + (doct >> 1)) << 8) + (ll << 4) + ((doct & 1) << 3)];
#pragma unroll
      for (int k = 0; k < 4; ++k)
        g[db][k] = hi * *(const half8*)&A16[k * 128 + doct * 8];
    }
    const half4 hit = *(const half4*)&hS[((s * 7 + 6) << 8) + (ll << 4) + lg * 4];
#pragma unroll
    for (int k = 0; k < 4; ++k)
      gt[k] = hit * *(const half4*)&A16[k * 128 + 96 + lg * 4];
    m = PADV; lsum = 0.f;
#pragma unroll
    for (int t = 0; t < 7; ++t) acc[t] = (f32x4){0.f, 0.f, 0.f, 0.f};
  };

  auto load_adj = [&](int jt) -> int4 {
    int jc = jt * 16 + lg * 4;
    if (jc > N_ - 4) jc = N_ - 4;
    return *(const int4*)(ajrow + jc);
  };

  auto tile_body = [&](int jt, int4 av, bool tail) {
    f32x4 c0 = {0.f, 0.f, 0.f, 0.f}, c1 = c0, c2 = c0, c3 = c0;
    __builtin_amdgcn_s_setprio(1);
#pragma unroll
    for (int db = 0; db < 3; ++db) {
      const int doct = db * 4 + lg;
      const half8 aj = *(const half8*)&hS[((jt * 7 + (doct >> 1)) << 8) + (ll << 4) + ((doct & 1) << 3)];
      c0 = __builtin_amdgcn_mfma_f32_16x16x32_f16(aj, g[db][0], c0, 0, 0, 0);
      c1 = __builtin_amdgcn_mfma_f32_16x16x32_f16(aj, g[db][1], c1, 0, 0, 0);
      c2 = __builtin_amdgcn_mfma_f32_16x16x32_f16(aj, g[db][2], c2, 0, 0, 0);
      c3 = __builtin_amdgcn_mfma_f32_16x16x32_f16(aj, g[db][3], c3, 0, 0, 0);
    }
    {
      const half4 ajt = *(const half4*)&hS[((jt * 7 + 6) << 8) + (ll << 4) + lg * 4];
      c0 = __builtin_amdgcn_mfma_f32_16x16x16f16(ajt, gt[0], c0, 0, 0, 0);
      c1 = __builtin_amdgcn_mfma_f32_16x16x16f16(ajt, gt[1], c1, 0, 0, 0);
      c2 = __builtin_amdgcn_mfma_f32_16x16x16f16(ajt, gt[2], c2, 0, 0, 0);
      c3 = __builtin_amdgcn_mfma_f32_16x16x16f16(ajt, gt[3], c3, 0, 0, 0);
    }
    __builtin_amdgcn_s_setprio(0);
    const int va[4] = {av.x, av.y, av.z, av.w};
    float sv[4];
#pragma unroll
    for (int r = 0; r < 4; ++r) {
      const float e = (va[r] == 1) ? c0[r] : (va[r] == 2) ? c1[r]
                     : (va[r] == 3) ? c2[r] : c3[r];
      sv[r] = (va[r] == 0) ? NEGINF : fmaxf(e, 0.2f * e);
    }
    if (tail && lg == 3) { sv[0] = PADV; sv[1] = PADV; sv[2] = PADV; sv[3] = PADV; }

    const unsigned trb = ldsbase + (unsigned)(jt * 3584) + trlane;
    half4 tr[7];
    TRD(tr[0], trb, 0);    TRD(tr[1], trb, 512);  TRD(tr[2], trb, 1024);
    TRD(tr[3], trb, 1536); TRD(tr[4], trb, 2048); TRD(tr[5], trb, 2560);
    TRD(tr[6], trb, 3072);

    const float lmax = fmaxf(fmaxf(sv[0], sv[1]), fmaxf(sv[2], sv[3]));
    if (__any(lmax > m + 8.f)) {
      float tmax = fmaxf(lmax, __shfl_xor(lmax, 16));
      tmax = fmaxf(tmax, __shfl_xor(tmax, 32));
      const float nm = fmaxf(m, tmax);
      const float f = exp2f(m - nm);
      m = nm; lsum *= f;
#pragma unroll
      for (int t = 0; t < 7; ++t) {
        acc[t][0] *= f; acc[t][1] *= f; acc[t][2] *= f; acc[t][3] *= f;
      }
    }
    const float p0 = exp2f(sv[0] - m), p1 = exp2f(sv[1] - m);
    const float p2 = exp2f(sv[2] - m), p3 = exp2f(sv[3] - m);
    lsum += (p0 + p1) + (p2 + p3);
    half4 pb;
    pb[0] = (_Float16)p0; pb[1] = (_Float16)p1;
    pb[2] = (_Float16)p2; pb[3] = (_Float16)p3;

    LGKM0;   // rule #18
    __builtin_amdgcn_s_setprio(1);
#pragma unroll
    for (int t = 0; t < 7; ++t)
      acc[t] = __builtin_amdgcn_mfma_f32_16x16x16f16(tr[t], pb, acc[t], 0, 0, 0);
    __builtin_amdgcn_s_setprio(0);
  };

  auto store_rows = [&](int s) {
    float ls = lsum;
    ls += __shfl_xor(ls, 16);
    ls += __shfl_xor(ls, 32);
    const float rv = 1.f / ls;
    const int irow = s * 16 + ll;
    if (irow < N_) {
      float* orow = OUT + ((size_t)b * N_ + irow) * E_;
#pragma unroll
      for (int t = 0; t < 7; ++t) {
        const int e0 = t * 16 + lg * 4;
        if (e0 < E_) {
          f32x4 o = acc[t];
          o[0] *= rv; o[1] *= rv; o[2] *= rv; o[3] *= rv;
          *(f32x4*)&orow[e0] = o;
        }
      }
    }
  };

  // ============ flattened tile-space: wave w owns units [30w, u1) ==========
  int u = 30 * w;
  const int u1 = (w == 11) ? 361 : (u + 30);
  bool held = false;
  int s_held = 0;

  while (u < u1) {
    const int s  = u / 19;
    const int j0 = u - 19 * s;
    const int j1 = (19 < j0 + (u1 - u)) ? 19 : (j0 + (u1 - u));
    prep_strip(s);
    int4 av = load_adj(j0);
    for (int jt = j0; jt < j1; ++jt) {
      const int4 nv = (jt + 1 < j1) ? load_adj(jt + 1) : av;
      tile_body(jt, av, jt == 18);
      av = nv;
    }
    if (j0 > 0) {
      // tail segment of a split strip -> write partial to region[w-1]
      float* dst = part + (size_t)(w - 1) * 1920 + lane * 30;
#pragma unroll
      for (int t = 0; t < 7; ++t) {
        dst[4 * t + 0] = acc[t][0]; dst[4 * t + 1] = acc[t][1];
        dst[4 * t + 2] = acc[t][2]; dst[4 * t + 3] = acc[t][3];
      }
      dst[28] = m; dst[29] = lsum;
    } else if (j1 < 19) {
      held = true; s_held = s;       // head segment: merge after barrier
    } else {
      store_rows(s);                 // whole strip
    }
    u += j1 - j0;
  }

  __syncthreads();

  if (held) {
    // merge region[w] (written by wave w+1's tail segment of s_held)
    const float* src = part + (size_t)w * 1920 + lane * 30;
    const float mq = src[28], lq = src[29];
    const float M  = fmaxf(m, mq);
    const float f0 = exp2f(m - M), f1 = exp2f(mq - M);
    m = M;
    lsum = lsum * f0 + lq * f1;
#pragma unroll
    for (int t = 0; t < 7; ++t) {
      acc[t][0] = acc[t][0] * f0 + src[4 * t + 0] * f1;
      acc[t][1] = acc[t][1] * f0 + src[4 * t + 1] * f1;
      acc[t][2] = acc[t][2] * f0 + src[4 * t + 2] * f1;
      acc[t][3] = acc[t][3] * f0 + src[4 * t + 3] * f1;
    }
    store_rows(s_held);
  }
}

extern "C" void kernel_launch(void* const* d_in, const int* in_sizes, int n_in,
                              void* d_out, int out_size, void* d_ws, size_t ws_size,
                              hipStream_t stream) {
  const float* H  = (const float*)d_in[0];
  const int*   AJ = (const int*)d_in[1];
  const float* A  = (const float*)d_in[2];
  float* OUT = (float*)d_out;

  (void)hipFuncSetAttribute(reinterpret_cast<const void*>(gat_final),
                            hipFuncAttributeMaxDynamicSharedMemorySize,
                            LDS_BYTES);
  gat_final<<<B_, 768, LDS_BYTES, stream>>>(H, AJ, A, OUT);
}